// Round 18
// baseline (96.123 us; speedup 1.0000x reference)
//
#include <hip/hip_runtime.h>
#include <math.h>

#define Bv  4
#define Cv  64
#define DCv 32
#define Fv  128
#define Tv  512
#define FT  (Fv * 512)

// bf16 helpers (RNE pack, shift-unpack)
__device__ __forceinline__ unsigned f2bf(float x) {
    unsigned u = __float_as_uint(x);
    return (u + 0x7FFFu + ((u >> 16) & 1u)) >> 16;
}
__device__ __forceinline__ float bflo(unsigned u) { return __uint_as_float(u << 16); }
__device__ __forceinline__ float bfhi(unsigned u) { return __uint_as_float(u & 0xFFFF0000u); }

#define DOT4(ACC, A, X) \
    ACC = fmaf(A.x, X.x, ACC); ACC = fmaf(A.y, X.y, ACC); \
    ACC = fmaf(A.z, X.z, ACC); ACC = fmaf(A.w, X.w, ACC);

// ---------------------------------------------------------------------------
// KPREP: fold BN into weights. W1T[k][c] (transposed, for kc1), B1f;
// W2f[o][k] (row-major, for kf), B2f.
// ---------------------------------------------------------------------------
__global__ __launch_bounds__(512)
void kprep(const float* __restrict__ w1, const float* __restrict__ b1,
           const float* __restrict__ g1, const float* __restrict__ be1,
           const float* __restrict__ m1, const float* __restrict__ v1,
           const float* __restrict__ wp, const float* __restrict__ bp,
           const float* __restrict__ g2, const float* __restrict__ be2,
           const float* __restrict__ m2, const float* __restrict__ v2,
           float* __restrict__ W1T, float* __restrict__ B1f,
           float* __restrict__ W2f, float* __restrict__ B2f)
{
    const int tid = threadIdx.x;
    #pragma unroll
    for (int i = 0; i < 4; ++i) {
        const int e = tid * 4 + i;          // W1T: e = k*32 + c
        const int c = e & 31, k = e >> 5;
        W1T[e] = w1[c * Cv + k] * (g1[c] * rsqrtf(v1[c] + 1e-5f));
    }
    {
        const int o = tid >> 3;             // 8 float4 per 32-wide row
        const float s = g2[o] * rsqrtf(v2[o] + 1e-5f);
        float4 v = *(const float4*)&wp[tid * 4];
        v.x *= s; v.y *= s; v.z *= s; v.w *= s;
        *(float4*)&W2f[tid * 4] = v;
    }
    if (tid < DCv) {
        const float s = g1[tid] * rsqrtf(v1[tid] + 1e-5f);
        B1f[tid] = (b1[tid] - m1[tid]) * s + be1[tid];
    }
    if (tid < Cv) {
        const float s = g2[tid] * rsqrtf(v2[tid] + 1e-5f);
        B2f[tid] = (bp[tid] - m2[tid]) * s + be2[tid];
    }
}

// ---------------------------------------------------------------------------
// KC1: conv1, 8-row x 4-t register tile (r17 proven, ~30 us). grid
// (bf, t-half) = 1024 x 256 (4 waves). Per k: 1 global b128 (32 FMA) +
// 2 broadcast LDS b128.
// ---------------------------------------------------------------------------
__global__ __launch_bounds__(256, 4)
void kc1_conv(const float* __restrict__ inp,
              const float* __restrict__ W1T, const float* __restrict__ B1f,
              const float* __restrict__ a1,
              float* __restrict__ Qws)
{
    __shared__ __align__(16) float sW[Cv * DCv];   // 8 KB [k][c]
    __shared__ float sB[DCv];

    const int tid = threadIdx.x;
    const int bid = blockIdx.x;
    const int h   = bid & 1;
    const int bf  = bid >> 1;
    const int b   = bf >> 7;
    const int f   = bf & 127;

    {
        const int e = tid * 8;
        *(float4*)&sW[e]     = *(const float4*)&W1T[e];
        *(float4*)&sW[e + 4] = *(const float4*)&W1T[e + 4];
    }
    if (tid < DCv) sB[tid] = B1f[tid];
    const float alpha1 = a1[0];
    __syncthreads();

    const int w  = tid >> 6, l = tid & 63;
    const int tl = l & 15, cl = l >> 4;
    const int r0 = cl * 8;
    const int t0 = h * 256 + w * 64 + tl * 4;

    const float* px = inp + (size_t)(b * Cv) * FT + f * 512 + t0;

    float acc[32];
    #pragma unroll
    for (int i = 0; i < 32; ++i) acc[i] = 0.f;

    #pragma unroll 8
    for (int k = 0; k < Cv; ++k) {
        const float4 x   = *(const float4*)&px[(size_t)k * FT];
        const float4 a0  = *(const float4*)&sW[k * DCv + r0];
        const float4 a1v = *(const float4*)&sW[k * DCv + r0 + 4];
        acc[0*4+0] = fmaf(a0.x, x.x, acc[0*4+0]); acc[0*4+1] = fmaf(a0.x, x.y, acc[0*4+1]);
        acc[0*4+2] = fmaf(a0.x, x.z, acc[0*4+2]); acc[0*4+3] = fmaf(a0.x, x.w, acc[0*4+3]);
        acc[1*4+0] = fmaf(a0.y, x.x, acc[1*4+0]); acc[1*4+1] = fmaf(a0.y, x.y, acc[1*4+1]);
        acc[1*4+2] = fmaf(a0.y, x.z, acc[1*4+2]); acc[1*4+3] = fmaf(a0.y, x.w, acc[1*4+3]);
        acc[2*4+0] = fmaf(a0.z, x.x, acc[2*4+0]); acc[2*4+1] = fmaf(a0.z, x.y, acc[2*4+1]);
        acc[2*4+2] = fmaf(a0.z, x.z, acc[2*4+2]); acc[2*4+3] = fmaf(a0.z, x.w, acc[2*4+3]);
        acc[3*4+0] = fmaf(a0.w, x.x, acc[3*4+0]); acc[3*4+1] = fmaf(a0.w, x.y, acc[3*4+1]);
        acc[3*4+2] = fmaf(a0.w, x.z, acc[3*4+2]); acc[3*4+3] = fmaf(a0.w, x.w, acc[3*4+3]);
        acc[4*4+0] = fmaf(a1v.x, x.x, acc[4*4+0]); acc[4*4+1] = fmaf(a1v.x, x.y, acc[4*4+1]);
        acc[4*4+2] = fmaf(a1v.x, x.z, acc[4*4+2]); acc[4*4+3] = fmaf(a1v.x, x.w, acc[4*4+3]);
        acc[5*4+0] = fmaf(a1v.y, x.x, acc[5*4+0]); acc[5*4+1] = fmaf(a1v.y, x.y, acc[5*4+1]);
        acc[5*4+2] = fmaf(a1v.y, x.z, acc[5*4+2]); acc[5*4+3] = fmaf(a1v.y, x.w, acc[5*4+3]);
        acc[6*4+0] = fmaf(a1v.z, x.x, acc[6*4+0]); acc[6*4+1] = fmaf(a1v.z, x.y, acc[6*4+1]);
        acc[6*4+2] = fmaf(a1v.z, x.z, acc[6*4+2]); acc[6*4+3] = fmaf(a1v.z, x.w, acc[6*4+3]);
        acc[7*4+0] = fmaf(a1v.w, x.x, acc[7*4+0]); acc[7*4+1] = fmaf(a1v.w, x.y, acc[7*4+1]);
        acc[7*4+2] = fmaf(a1v.w, x.z, acc[7*4+2]); acc[7*4+3] = fmaf(a1v.w, x.w, acc[7*4+3]);
    }

    const float b0 = sB[r0+0], b1_ = sB[r0+1], b2 = sB[r0+2], b3 = sB[r0+3];
    const float b4 = sB[r0+4], b5  = sB[r0+5], b6 = sB[r0+6], b7 = sB[r0+7];
    #pragma unroll
    for (int j = 0; j < 4; ++j) {
        float z0 = acc[0*4+j] + b0, z1 = acc[1*4+j] + b1_;
        float z2 = acc[2*4+j] + b2, z3 = acc[3*4+j] + b3;
        float z4 = acc[4*4+j] + b4, z5 = acc[5*4+j] + b5;
        float z6 = acc[6*4+j] + b6, z7 = acc[7*4+j] + b7;
        z0 = z0 >= 0.f ? z0 : alpha1 * z0;  z1 = z1 >= 0.f ? z1 : alpha1 * z1;
        z2 = z2 >= 0.f ? z2 : alpha1 * z2;  z3 = z3 >= 0.f ? z3 : alpha1 * z3;
        z4 = z4 >= 0.f ? z4 : alpha1 * z4;  z5 = z5 >= 0.f ? z5 : alpha1 * z5;
        z6 = z6 >= 0.f ? z6 : alpha1 * z6;  z7 = z7 >= 0.f ? z7 : alpha1 * z7;
        float4 v0; v0.x = z0; v0.y = z1; v0.z = z2; v0.w = z3;
        float4 v1; v1.x = z4; v1.y = z5; v1.z = z6; v1.w = z7;
        float* qg = Qws + ((size_t)bf * Tv + t0 + j) * DCv + r0;
        *(float4*)&qg[0] = v0;
        *(float4*)&qg[4] = v1;
    }
}

// ---------------------------------------------------------------------------
// KM: M = Q Q^T / sqrt(32). One block per bf. Proven (~9 us, 60 TF).
// ---------------------------------------------------------------------------
__global__ __launch_bounds__(256)
void km_build(const float* __restrict__ Qws, float* __restrict__ Mfull)
{
    __shared__ __align__(16) float sP[4][1024];  // 16 KB

    const int tid   = threadIdx.x;
    const int bf    = blockIdx.x;
    const int slice = tid >> 6;
    const int l     = tid & 63;
    const int c1b   = l >> 3;
    const int c2b   = l & 7;

    const float* qp = Qws + ((size_t)bf * Tv + slice * 128) * DCv;
    float4 r0 = {0,0,0,0}, r1 = {0,0,0,0}, r2 = {0,0,0,0}, r3 = {0,0,0,0};
    #pragma unroll 4
    for (int i = 0; i < 128; ++i) {
        const float4 qa = *(const float4*)&qp[i * 32 + c1b * 4];
        const float4 qb = *(const float4*)&qp[i * 32 + c2b * 4];
        r0.x = fmaf(qa.x, qb.x, r0.x); r0.y = fmaf(qa.x, qb.y, r0.y);
        r0.z = fmaf(qa.x, qb.z, r0.z); r0.w = fmaf(qa.x, qb.w, r0.w);
        r1.x = fmaf(qa.y, qb.x, r1.x); r1.y = fmaf(qa.y, qb.y, r1.y);
        r1.z = fmaf(qa.y, qb.z, r1.z); r1.w = fmaf(qa.y, qb.w, r1.w);
        r2.x = fmaf(qa.z, qb.x, r2.x); r2.y = fmaf(qa.z, qb.y, r2.y);
        r2.z = fmaf(qa.z, qb.z, r2.z); r2.w = fmaf(qa.z, qb.w, r2.w);
        r3.x = fmaf(qa.w, qb.x, r3.x); r3.y = fmaf(qa.w, qb.y, r3.y);
        r3.z = fmaf(qa.w, qb.z, r3.z); r3.w = fmaf(qa.w, qb.w, r3.w);
    }
    *(float4*)&sP[slice][(c1b * 4 + 0) * DCv + c2b * 4] = r0;
    *(float4*)&sP[slice][(c1b * 4 + 1) * DCv + c2b * 4] = r1;
    *(float4*)&sP[slice][(c1b * 4 + 2) * DCv + c2b * 4] = r2;
    *(float4*)&sP[slice][(c1b * 4 + 3) * DCv + c2b * 4] = r3;
    __syncthreads();

    const float INV = 0.17677669529663687f;  // 1/sqrt(32)
    float4 v0 = *(const float4*)&sP[0][tid * 4];
    float4 v1 = *(const float4*)&sP[1][tid * 4];
    float4 v2 = *(const float4*)&sP[2][tid * 4];
    float4 v3 = *(const float4*)&sP[3][tid * 4];
    float4 o;
    o.x = ((v0.x + v1.x) + (v2.x + v3.x)) * INV;
    o.y = ((v0.y + v1.y) + (v2.y + v3.y)) * INV;
    o.z = ((v0.z + v1.z) + (v2.z + v3.z)) * INV;
    o.w = ((v0.w + v1.w) + (v2.w + v3.w)) * INV;
    *(float4*)&Mfull[(size_t)bf * 1024 + tid * 4] = o;
}

// ---------------------------------------------------------------------------
// KF v3: fused O=M*Q -> mask -> softmax -> P(bf16) -> OUT=W2f*P+B2f -> PReLU
// -> +residual. Changes vs r16 (48.7 us): NO Q staging (GEMM1 x straight from
// global Qws[t][k], L2-hot, dot-form); P stored bf16 [32][520] (33 KB LDS,
// GEMM2 x = uint2 reads); residual streamed per-row in epilogue. LDS instr
// ~300 -> ~170 per thread; staging regs freed (r17 spill source).
// ---------------------------------------------------------------------------
__global__ __launch_bounds__(512, 2)
void kf_fused(const float* __restrict__ inp,
              const float* __restrict__ Qws, const float* __restrict__ Mfull,
              const float* __restrict__ W2f, const float* __restrict__ B2f,
              const float* __restrict__ a2,
              float* __restrict__ out)
{
    __shared__ __align__(16) unsigned short sPb[DCv * 520];  // 33.3 KB bf16 P [c][t]
    __shared__ __align__(16) float sM[DCv * 36];   // 4.5 KB
    __shared__ __align__(16) float sW[Cv * 36];    // 9 KB
    __shared__ float sPart[8][DCv];
    __shared__ float sMx[DCv], sRZ[DCv];
    __shared__ float sB2[Cv];

    const int tid = threadIdx.x;
    const int bf  = blockIdx.x;
    const int b   = bf >> 7;
    const int f   = bf & 127;
    const int w   = tid >> 6;
    const int l   = tid & 63;
    const int tl  = l & 15;
    const int cl  = l >> 4;
    const int t0  = w * 64 + tl * 4;          // this lane's 4 t-columns
    const int limit = f + (Tv - Fv + 1);      // valid iff t < limit (385..512)
    const float alpha2 = a2[0];

    // ---- stage: M, W2f, B2f (no Q staging) ----
    if (tid < 256) {
        const int c = tid >> 3, k0 = (tid & 7) << 2;
        float4 v = *(const float4*)&Mfull[(size_t)bf * 1024 + tid * 4];
        *(float4*)&sM[c * 36 + k0] = v;
    }
    {
        const int c = tid >> 3, k0 = (tid & 7) << 2;
        float4 v = *(const float4*)&W2f[tid * 4];
        *(float4*)&sW[c * 36 + k0] = v;
    }
    if (tid < Cv) sB2[tid] = B2f[tid];
    __syncthreads();

    // ---- GEMM1 (dot form): oX[cc][j] = sum_k M[row][k] * Q[t0+j][k] ----
    const float* Qb = Qws + (size_t)bf * Tv * DCv;   // [t][k]
    float oA[16], oB[16];
    #pragma unroll
    for (int i = 0; i < 16; ++i) { oA[i] = 0.f; oB[i] = 0.f; }
    const int cA = cl * 4;
    const int cB = 16 + cl * 4;
    #pragma unroll
    for (int k0 = 0; k0 < 32; k0 += 4) {
        const float4 x0 = *(const float4*)&Qb[(t0+0) * DCv + k0];
        const float4 x1 = *(const float4*)&Qb[(t0+1) * DCv + k0];
        const float4 x2 = *(const float4*)&Qb[(t0+2) * DCv + k0];
        const float4 x3 = *(const float4*)&Qb[(t0+3) * DCv + k0];
        { const float4 a = *(const float4*)&sM[(cA+0)*36 + k0];
          DOT4(oA[0],  a, x0) DOT4(oA[1],  a, x1) DOT4(oA[2],  a, x2) DOT4(oA[3],  a, x3) }
        { const float4 a = *(const float4*)&sM[(cA+1)*36 + k0];
          DOT4(oA[4],  a, x0) DOT4(oA[5],  a, x1) DOT4(oA[6],  a, x2) DOT4(oA[7],  a, x3) }
        { const float4 a = *(const float4*)&sM[(cA+2)*36 + k0];
          DOT4(oA[8],  a, x0) DOT4(oA[9],  a, x1) DOT4(oA[10], a, x2) DOT4(oA[11], a, x3) }
        { const float4 a = *(const float4*)&sM[(cA+3)*36 + k0];
          DOT4(oA[12], a, x0) DOT4(oA[13], a, x1) DOT4(oA[14], a, x2) DOT4(oA[15], a, x3) }
        { const float4 a = *(const float4*)&sM[(cB+0)*36 + k0];
          DOT4(oB[0],  a, x0) DOT4(oB[1],  a, x1) DOT4(oB[2],  a, x2) DOT4(oB[3],  a, x3) }
        { const float4 a = *(const float4*)&sM[(cB+1)*36 + k0];
          DOT4(oB[4],  a, x0) DOT4(oB[5],  a, x1) DOT4(oB[6],  a, x2) DOT4(oB[7],  a, x3) }
        { const float4 a = *(const float4*)&sM[(cB+2)*36 + k0];
          DOT4(oB[8],  a, x0) DOT4(oB[9],  a, x1) DOT4(oB[10], a, x2) DOT4(oB[11], a, x3) }
        { const float4 a = *(const float4*)&sM[(cB+3)*36 + k0];
          DOT4(oB[12], a, x0) DOT4(oB[13], a, x1) DOT4(oB[14], a, x2) DOT4(oB[15], a, x3) }
    }

    // ---- mask (lane's t-col jt: oX[cc*4+jt]) ----
    #pragma unroll
    for (int jt = 0; jt < 4; ++jt) {
        if (t0 + jt >= limit) {
            #pragma unroll
            for (int cc = 0; cc < 4; ++cc) { oA[cc*4+jt] = -INFINITY; oB[cc*4+jt] = -INFINITY; }
        }
    }

    // ---- stats pass 1: per-(wave,c) max ----
    #pragma unroll
    for (int cc = 0; cc < 4; ++cc) {
        float mA = fmaxf(fmaxf(oA[cc*4+0], oA[cc*4+1]), fmaxf(oA[cc*4+2], oA[cc*4+3]));
        float mB = fmaxf(fmaxf(oB[cc*4+0], oB[cc*4+1]), fmaxf(oB[cc*4+2], oB[cc*4+3]));
        #pragma unroll
        for (int s = 1; s < 16; s <<= 1) {
            mA = fmaxf(mA, __shfl_xor(mA, s));
            mB = fmaxf(mB, __shfl_xor(mB, s));
        }
        if (tl == 0) { sPart[w][cA + cc] = mA; sPart[w][cB + cc] = mB; }
    }
    __syncthreads();
    if (tid < DCv) {
        float m = sPart[0][tid];
        #pragma unroll
        for (int ww = 1; ww < 8; ++ww) m = fmaxf(m, sPart[ww][tid]);
        sMx[tid] = m;
    }
    __syncthreads();

    // ---- exp + pass 2: per-(wave,c) sum ----
    #pragma unroll
    for (int cc = 0; cc < 4; ++cc) {
        const float mxA = sMx[cA + cc], mxB = sMx[cB + cc];
        float sA = 0.f, sB = 0.f;
        #pragma unroll
        for (int jt = 0; jt < 4; ++jt) {
            oA[cc*4+jt] = __expf(oA[cc*4+jt] - mxA); sA += oA[cc*4+jt];
            oB[cc*4+jt] = __expf(oB[cc*4+jt] - mxB); sB += oB[cc*4+jt];
        }
        #pragma unroll
        for (int s = 1; s < 16; s <<= 1) {
            sA += __shfl_xor(sA, s);
            sB += __shfl_xor(sB, s);
        }
        if (tl == 0) { sPart[w][cA + cc] = sA; sPart[w][cB + cc] = sB; }
    }
    __syncthreads();
    if (tid < DCv) {
        float z = 0.f;
        #pragma unroll
        for (int ww = 0; ww < 8; ++ww) z += sPart[ww][tid];
        sRZ[tid] = 1.f / z;
    }
    __syncthreads();

    // ---- P = e * rz -> bf16 into sPb[c][t] ----
    #pragma unroll
    for (int cc = 0; cc < 4; ++cc) {
        const float rA = sRZ[cA + cc], rB = sRZ[cB + cc];
        uint2 wA, wB;
        wA.x = f2bf(oA[cc*4+0]*rA) | (f2bf(oA[cc*4+1]*rA) << 16);
        wA.y = f2bf(oA[cc*4+2]*rA) | (f2bf(oA[cc*4+3]*rA) << 16);
        wB.x = f2bf(oB[cc*4+0]*rB) | (f2bf(oB[cc*4+1]*rB) << 16);
        wB.y = f2bf(oB[cc*4+2]*rB) | (f2bf(oB[cc*4+3]*rB) << 16);
        *(uint2*)&sPb[(cA + cc) * 520 + t0] = wA;
        *(uint2*)&sPb[(cB + cc) * 520 + t0] = wB;
    }
    __syncthreads();

    // ---- GEMM2: OUT[64oc][t], two 8-row-tile iterations, bf16 x ----
    #pragma unroll 1
    for (int it = 0; it < 2; ++it) {
        const int oc0 = it * 32 + cl * 8;

        float acc[32];
        #pragma unroll
        for (int i = 0; i < 32; ++i) acc[i] = 0.f;

        #pragma unroll
        for (int k0 = 0; k0 < 32; k0 += 4) {
            const uint2 p0 = *(const uint2*)&sPb[(k0+0) * 520 + t0];
            const uint2 p1 = *(const uint2*)&sPb[(k0+1) * 520 + t0];
            const uint2 p2 = *(const uint2*)&sPb[(k0+2) * 520 + t0];
            const uint2 p3 = *(const uint2*)&sPb[(k0+3) * 520 + t0];
            float4 xt0, xt1, xt2, xt3;   // float4 over kk, one per t-col
            xt0.x = bflo(p0.x); xt0.y = bflo(p1.x); xt0.z = bflo(p2.x); xt0.w = bflo(p3.x);
            xt1.x = bfhi(p0.x); xt1.y = bfhi(p1.x); xt1.z = bfhi(p2.x); xt1.w = bfhi(p3.x);
            xt2.x = bflo(p0.y); xt2.y = bflo(p1.y); xt2.z = bflo(p2.y); xt2.w = bflo(p3.y);
            xt3.x = bfhi(p0.y); xt3.y = bfhi(p1.y); xt3.z = bfhi(p2.y); xt3.w = bfhi(p3.y);
            { const float4 a = *(const float4*)&sW[(oc0+0)*36 + k0];
              DOT4(acc[0],  a, xt0) DOT4(acc[1],  a, xt1) DOT4(acc[2],  a, xt2) DOT4(acc[3],  a, xt3) }
            { const float4 a = *(const float4*)&sW[(oc0+1)*36 + k0];
              DOT4(acc[4],  a, xt0) DOT4(acc[5],  a, xt1) DOT4(acc[6],  a, xt2) DOT4(acc[7],  a, xt3) }
            { const float4 a = *(const float4*)&sW[(oc0+2)*36 + k0];
              DOT4(acc[8],  a, xt0) DOT4(acc[9],  a, xt1) DOT4(acc[10], a, xt2) DOT4(acc[11], a, xt3) }
            { const float4 a = *(const float4*)&sW[(oc0+3)*36 + k0];
              DOT4(acc[12], a, xt0) DOT4(acc[13], a, xt1) DOT4(acc[14], a, xt2) DOT4(acc[15], a, xt3) }
            { const float4 a = *(const float4*)&sW[(oc0+4)*36 + k0];
              DOT4(acc[16], a, xt0) DOT4(acc[17], a, xt1) DOT4(acc[18], a, xt2) DOT4(acc[19], a, xt3) }
            { const float4 a = *(const float4*)&sW[(oc0+5)*36 + k0];
              DOT4(acc[20], a, xt0) DOT4(acc[21], a, xt1) DOT4(acc[22], a, xt2) DOT4(acc[23], a, xt3) }
            { const float4 a = *(const float4*)&sW[(oc0+6)*36 + k0];
              DOT4(acc[24], a, xt0) DOT4(acc[25], a, xt1) DOT4(acc[26], a, xt2) DOT4(acc[27], a, xt3) }
            { const float4 a = *(const float4*)&sW[(oc0+7)*36 + k0];
              DOT4(acc[28], a, xt0) DOT4(acc[29], a, xt1) DOT4(acc[30], a, xt2) DOT4(acc[31], a, xt3) }
        }

        // epilogue: residual streamed per row (low live-reg)
        const float* rp = inp + ((size_t)(b * Cv + oc0) * Fv + f) * Tv + t0;
        float*       po = out + ((size_t)(b * Cv + oc0) * Fv + f) * Tv + t0;
        #pragma unroll
        for (int r = 0; r < 8; ++r) {
            const float4 rv = *(const float4*)&rp[(size_t)r * FT];
            const float bb = sB2[oc0 + r];
            float z0 = acc[r*4+0] + bb, z1 = acc[r*4+1] + bb;
            float z2 = acc[r*4+2] + bb, z3 = acc[r*4+3] + bb;
            z0 = z0 >= 0.f ? z0 : alpha2 * z0;
            z1 = z1 >= 0.f ? z1 : alpha2 * z1;
            z2 = z2 >= 0.f ? z2 : alpha2 * z2;
            z3 = z3 >= 0.f ? z3 : alpha2 * z3;
            float4 o4; o4.x = z0 + rv.x; o4.y = z1 + rv.y;
            o4.z = z2 + rv.z; o4.w = z3 + rv.w;
            *(float4*)&po[(size_t)r * FT] = o4;
        }
    }
}

extern "C" void kernel_launch(void* const* d_in, const int* in_sizes, int n_in,
                              void* d_out, int out_size, void* d_ws, size_t ws_size,
                              hipStream_t stream) {
    const float* inp = (const float*)d_in[0];
    const float* w1  = (const float*)d_in[1];
    const float* b1  = (const float*)d_in[2];
    const float* g1  = (const float*)d_in[3];
    const float* be1 = (const float*)d_in[4];
    const float* m1  = (const float*)d_in[5];
    const float* v1  = (const float*)d_in[6];
    const float* a1  = (const float*)d_in[7];
    const float* wp  = (const float*)d_in[8];
    const float* bp  = (const float*)d_in[9];
    const float* g2  = (const float*)d_in[10];
    const float* be2 = (const float*)d_in[11];
    const float* m2  = (const float*)d_in[12];
    const float* v2  = (const float*)d_in[13];
    const float* a2  = (const float*)d_in[14];

    float* Qws   = (float*)d_ws;                            // 8,388,608 f = 33.6 MB
    float* Mfull = Qws   + (size_t)Bv * Fv * Tv * DCv;      //   524,288 f =  2.1 MB
    float* W1T   = Mfull + (size_t)512 * 1024;              //     2,048 f
    float* B1f   = W1T   + 2048;                            //        32 f
    float* W2f   = B1f   + 32;                              //     2,048 f
    float* B2f   = W2f   + 2048;                            //        64 f

    kprep<<<dim3(1), dim3(512), 0, stream>>>(
        w1, b1, g1, be1, m1, v1, wp, bp, g2, be2, m2, v2, W1T, B1f, W2f, B2f);
    kc1_conv<<<dim3(Bv * Fv * 2), dim3(256), 0, stream>>>(inp, W1T, B1f, a1, Qws);
    km_build<<<dim3(Bv * Fv), dim3(256), 0, stream>>>(Qws, Mfull);
    kf_fused<<<dim3(Bv * Fv), dim3(512), 0, stream>>>(
        inp, Qws, Mfull, W2f, B2f, a2, (float*)d_out);
}

// Round 19
// 87.339 us; speedup vs baseline: 1.1006x; 1.1006x over previous
//
#include <hip/hip_runtime.h>
#include <math.h>

#define Bv  4
#define Cv  64
#define DCv 32
#define Fv  128
#define Tv  512
#define FT  (Fv * 512)

// ---------------------------------------------------------------------------
// KC1: conv1, 8-row x 4-t register tile (r17-measured ~30 us). grid
// (bf, t-half) = 1024 x 256 (4 waves). Per k: 1 global b128 (32 FMA) +
// 2 broadcast LDS b128. BN fold computed INLINE (kprep removed).
// ---------------------------------------------------------------------------
__global__ __launch_bounds__(256, 4)
void kc1_conv(const float* __restrict__ inp,
              const float* __restrict__ w1, const float* __restrict__ b1,
              const float* __restrict__ g1, const float* __restrict__ be1,
              const float* __restrict__ m1, const float* __restrict__ v1,
              const float* __restrict__ a1,
              float* __restrict__ Qws)
{
    __shared__ __align__(16) float sW[Cv * DCv];   // 8 KB [k][c]
    __shared__ float sB[DCv];

    const int tid = threadIdx.x;
    const int bid = blockIdx.x;
    const int h   = bid & 1;
    const int bf  = bid >> 1;
    const int b   = bf >> 7;
    const int f   = bf & 127;

    // inline BN-folded, transposed W1 stage: sW[k*32+c] = w1[c][k] * s1(c)
    #pragma unroll
    for (int i = 0; i < 8; ++i) {
        const int e = tid * 8 + i;
        const int c = e & 31, k = e >> 5;
        sW[e] = w1[c * Cv + k] * (g1[c] * rsqrtf(v1[c] + 1e-5f));
    }
    if (tid < DCv) {
        const float s = g1[tid] * rsqrtf(v1[tid] + 1e-5f);
        sB[tid] = (b1[tid] - m1[tid]) * s + be1[tid];
    }
    const float alpha1 = a1[0];
    __syncthreads();

    const int w  = tid >> 6, l = tid & 63;
    const int tl = l & 15, cl = l >> 4;
    const int r0 = cl * 8;
    const int t0 = h * 256 + w * 64 + tl * 4;

    const float* px = inp + (size_t)(b * Cv) * FT + f * 512 + t0;

    float acc[32];
    #pragma unroll
    for (int i = 0; i < 32; ++i) acc[i] = 0.f;

    #pragma unroll 8
    for (int k = 0; k < Cv; ++k) {
        const float4 x   = *(const float4*)&px[(size_t)k * FT];
        const float4 a0  = *(const float4*)&sW[k * DCv + r0];
        const float4 a1v = *(const float4*)&sW[k * DCv + r0 + 4];
        acc[0*4+0] = fmaf(a0.x, x.x, acc[0*4+0]); acc[0*4+1] = fmaf(a0.x, x.y, acc[0*4+1]);
        acc[0*4+2] = fmaf(a0.x, x.z, acc[0*4+2]); acc[0*4+3] = fmaf(a0.x, x.w, acc[0*4+3]);
        acc[1*4+0] = fmaf(a0.y, x.x, acc[1*4+0]); acc[1*4+1] = fmaf(a0.y, x.y, acc[1*4+1]);
        acc[1*4+2] = fmaf(a0.y, x.z, acc[1*4+2]); acc[1*4+3] = fmaf(a0.y, x.w, acc[1*4+3]);
        acc[2*4+0] = fmaf(a0.z, x.x, acc[2*4+0]); acc[2*4+1] = fmaf(a0.z, x.y, acc[2*4+1]);
        acc[2*4+2] = fmaf(a0.z, x.z, acc[2*4+2]); acc[2*4+3] = fmaf(a0.z, x.w, acc[2*4+3]);
        acc[3*4+0] = fmaf(a0.w, x.x, acc[3*4+0]); acc[3*4+1] = fmaf(a0.w, x.y, acc[3*4+1]);
        acc[3*4+2] = fmaf(a0.w, x.z, acc[3*4+2]); acc[3*4+3] = fmaf(a0.w, x.w, acc[3*4+3]);
        acc[4*4+0] = fmaf(a1v.x, x.x, acc[4*4+0]); acc[4*4+1] = fmaf(a1v.x, x.y, acc[4*4+1]);
        acc[4*4+2] = fmaf(a1v.x, x.z, acc[4*4+2]); acc[4*4+3] = fmaf(a1v.x, x.w, acc[4*4+3]);
        acc[5*4+0] = fmaf(a1v.y, x.x, acc[5*4+0]); acc[5*4+1] = fmaf(a1v.y, x.y, acc[5*4+1]);
        acc[5*4+2] = fmaf(a1v.y, x.z, acc[5*4+2]); acc[5*4+3] = fmaf(a1v.y, x.w, acc[5*4+3]);
        acc[6*4+0] = fmaf(a1v.z, x.x, acc[6*4+0]); acc[6*4+1] = fmaf(a1v.z, x.y, acc[6*4+1]);
        acc[6*4+2] = fmaf(a1v.z, x.z, acc[6*4+2]); acc[6*4+3] = fmaf(a1v.z, x.w, acc[6*4+3]);
        acc[7*4+0] = fmaf(a1v.w, x.x, acc[7*4+0]); acc[7*4+1] = fmaf(a1v.w, x.y, acc[7*4+1]);
        acc[7*4+2] = fmaf(a1v.w, x.z, acc[7*4+2]); acc[7*4+3] = fmaf(a1v.w, x.w, acc[7*4+3]);
    }

    const float b0 = sB[r0+0], b1_ = sB[r0+1], b2 = sB[r0+2], b3 = sB[r0+3];
    const float b4 = sB[r0+4], b5  = sB[r0+5], b6 = sB[r0+6], b7 = sB[r0+7];
    #pragma unroll
    for (int j = 0; j < 4; ++j) {
        float z0 = acc[0*4+j] + b0, z1 = acc[1*4+j] + b1_;
        float z2 = acc[2*4+j] + b2, z3 = acc[3*4+j] + b3;
        float z4 = acc[4*4+j] + b4, z5 = acc[5*4+j] + b5;
        float z6 = acc[6*4+j] + b6, z7 = acc[7*4+j] + b7;
        z0 = z0 >= 0.f ? z0 : alpha1 * z0;  z1 = z1 >= 0.f ? z1 : alpha1 * z1;
        z2 = z2 >= 0.f ? z2 : alpha1 * z2;  z3 = z3 >= 0.f ? z3 : alpha1 * z3;
        z4 = z4 >= 0.f ? z4 : alpha1 * z4;  z5 = z5 >= 0.f ? z5 : alpha1 * z5;
        z6 = z6 >= 0.f ? z6 : alpha1 * z6;  z7 = z7 >= 0.f ? z7 : alpha1 * z7;
        float4 v0; v0.x = z0; v0.y = z1; v0.z = z2; v0.w = z3;
        float4 v1; v1.x = z4; v1.y = z5; v1.z = z6; v1.w = z7;
        float* qg = Qws + ((size_t)bf * Tv + t0 + j) * DCv + r0;
        *(float4*)&qg[0] = v0;
        *(float4*)&qg[4] = v1;
    }
}

// ---------------------------------------------------------------------------
// KM: M = Q Q^T / sqrt(32). One block per bf. Proven (~9 us, 60 TF).
// ---------------------------------------------------------------------------
__global__ __launch_bounds__(256)
void km_build(const float* __restrict__ Qws, float* __restrict__ Mfull)
{
    __shared__ __align__(16) float sP[4][1024];  // 16 KB

    const int tid   = threadIdx.x;
    const int bf    = blockIdx.x;
    const int slice = tid >> 6;
    const int l     = tid & 63;
    const int c1b   = l >> 3;
    const int c2b   = l & 7;

    const float* qp = Qws + ((size_t)bf * Tv + slice * 128) * DCv;
    float4 r0 = {0,0,0,0}, r1 = {0,0,0,0}, r2 = {0,0,0,0}, r3 = {0,0,0,0};
    #pragma unroll 4
    for (int i = 0; i < 128; ++i) {
        const float4 qa = *(const float4*)&qp[i * 32 + c1b * 4];
        const float4 qb = *(const float4*)&qp[i * 32 + c2b * 4];
        r0.x = fmaf(qa.x, qb.x, r0.x); r0.y = fmaf(qa.x, qb.y, r0.y);
        r0.z = fmaf(qa.x, qb.z, r0.z); r0.w = fmaf(qa.x, qb.w, r0.w);
        r1.x = fmaf(qa.y, qb.x, r1.x); r1.y = fmaf(qa.y, qb.y, r1.y);
        r1.z = fmaf(qa.y, qb.z, r1.z); r1.w = fmaf(qa.y, qb.w, r1.w);
        r2.x = fmaf(qa.z, qb.x, r2.x); r2.y = fmaf(qa.z, qb.y, r2.y);
        r2.z = fmaf(qa.z, qb.z, r2.z); r2.w = fmaf(qa.z, qb.w, r2.w);
        r3.x = fmaf(qa.w, qb.x, r3.x); r3.y = fmaf(qa.w, qb.y, r3.y);
        r3.z = fmaf(qa.w, qb.z, r3.z); r3.w = fmaf(qa.w, qb.w, r3.w);
    }
    *(float4*)&sP[slice][(c1b * 4 + 0) * DCv + c2b * 4] = r0;
    *(float4*)&sP[slice][(c1b * 4 + 1) * DCv + c2b * 4] = r1;
    *(float4*)&sP[slice][(c1b * 4 + 2) * DCv + c2b * 4] = r2;
    *(float4*)&sP[slice][(c1b * 4 + 3) * DCv + c2b * 4] = r3;
    __syncthreads();

    const float INV = 0.17677669529663687f;  // 1/sqrt(32)
    float4 v0 = *(const float4*)&sP[0][tid * 4];
    float4 v1 = *(const float4*)&sP[1][tid * 4];
    float4 v2 = *(const float4*)&sP[2][tid * 4];
    float4 v3 = *(const float4*)&sP[3][tid * 4];
    float4 o;
    o.x = ((v0.x + v1.x) + (v2.x + v3.x)) * INV;
    o.y = ((v0.y + v1.y) + (v2.y + v3.y)) * INV;
    o.z = ((v0.z + v1.z) + (v2.z + v3.z)) * INV;
    o.w = ((v0.w + v1.w) + (v2.w + v3.w)) * INV;
    *(float4*)&Mfull[(size_t)bf * 1024 + tid * 4] = o;
}

// ---------------------------------------------------------------------------
// KF: fused O=M*Q -> mask -> softmax -> P -> OUT=W2*P+B2 -> PReLU ->
// +residual. EXACT r17-measured 48.7us structure; only the W2/B2 stage now
// computes the BN fold inline from wp/bp/g2/... (kprep removed).
// ---------------------------------------------------------------------------
#define GEMM_CC(ACC, cc, a)                                       \
    ACC[(cc)*4+0] = fmaf(a.x, x0.x, ACC[(cc)*4+0]);               \
    ACC[(cc)*4+0] = fmaf(a.y, x1.x, ACC[(cc)*4+0]);               \
    ACC[(cc)*4+0] = fmaf(a.z, x2.x, ACC[(cc)*4+0]);               \
    ACC[(cc)*4+0] = fmaf(a.w, x3.x, ACC[(cc)*4+0]);               \
    ACC[(cc)*4+1] = fmaf(a.x, x0.y, ACC[(cc)*4+1]);               \
    ACC[(cc)*4+1] = fmaf(a.y, x1.y, ACC[(cc)*4+1]);               \
    ACC[(cc)*4+1] = fmaf(a.z, x2.y, ACC[(cc)*4+1]);               \
    ACC[(cc)*4+1] = fmaf(a.w, x3.y, ACC[(cc)*4+1]);               \
    ACC[(cc)*4+2] = fmaf(a.x, x0.z, ACC[(cc)*4+2]);               \
    ACC[(cc)*4+2] = fmaf(a.y, x1.z, ACC[(cc)*4+2]);               \
    ACC[(cc)*4+2] = fmaf(a.z, x2.z, ACC[(cc)*4+2]);               \
    ACC[(cc)*4+2] = fmaf(a.w, x3.z, ACC[(cc)*4+2]);               \
    ACC[(cc)*4+3] = fmaf(a.x, x0.w, ACC[(cc)*4+3]);               \
    ACC[(cc)*4+3] = fmaf(a.y, x1.w, ACC[(cc)*4+3]);               \
    ACC[(cc)*4+3] = fmaf(a.z, x2.w, ACC[(cc)*4+3]);               \
    ACC[(cc)*4+3] = fmaf(a.w, x3.w, ACC[(cc)*4+3]);

__global__ __launch_bounds__(512, 2)
void kf_fused(const float* __restrict__ inp,
              const float* __restrict__ Qws, const float* __restrict__ Mfull,
              const float* __restrict__ wp, const float* __restrict__ bp,
              const float* __restrict__ g2, const float* __restrict__ be2,
              const float* __restrict__ m2, const float* __restrict__ v2,
              const float* __restrict__ a2,
              float* __restrict__ out)
{
    __shared__ __align__(16) float sX[DCv * Tv];   // 64 KB [k][t]: Q, then P
    __shared__ __align__(16) float sM[DCv * 36];   // 4.5 KB
    __shared__ __align__(16) float sW[Cv * 36];    // 9 KB
    __shared__ float sPart[8][DCv];
    __shared__ float sMx[DCv], sRZ[DCv];
    __shared__ float sB2[Cv];

    const int tid = threadIdx.x;
    const int bf  = blockIdx.x;
    const int b   = bf >> 7;
    const int f   = bf & 127;
    const int w   = tid >> 6;
    const int l   = tid & 63;
    const int tl  = l & 15;
    const int cl  = l >> 4;
    const int t0  = w * 64 + tl * 4;          // this lane's 4 t-columns
    const int limit = f + (Tv - Fv + 1);      // valid iff t < limit (385..512)
    const float alpha2 = a2[0];

    // ---- stage: q column, M, W2 (BN-folded inline), B2 ----
    const float* qg = Qws + ((size_t)bf * Tv + tid) * DCv;
    float4 q0 = *(const float4*)&qg[0],  q1 = *(const float4*)&qg[4];
    float4 q2 = *(const float4*)&qg[8],  q3 = *(const float4*)&qg[12];
    float4 q4 = *(const float4*)&qg[16], q5 = *(const float4*)&qg[20];
    float4 q6 = *(const float4*)&qg[24], q7 = *(const float4*)&qg[28];

    if (tid < 256) {
        const int c = tid >> 3, k0 = (tid & 7) << 2;
        float4 v = *(const float4*)&Mfull[(size_t)bf * 1024 + tid * 4];
        *(float4*)&sM[c * 36 + k0] = v;
    }
    {
        const int c = tid >> 3, k0 = (tid & 7) << 2;
        const float s = g2[c] * rsqrtf(v2[c] + 1e-5f);
        float4 v = *(const float4*)&wp[tid * 4];
        v.x *= s; v.y *= s; v.z *= s; v.w *= s;
        *(float4*)&sW[c * 36 + k0] = v;
    }
    if (tid < Cv) {
        const float s = g2[tid] * rsqrtf(v2[tid] + 1e-5f);
        sB2[tid] = (bp[tid] - m2[tid]) * s + be2[tid];
    }

    {
        const int t = tid;
        sX[ 0*Tv+t]=q0.x; sX[ 1*Tv+t]=q0.y; sX[ 2*Tv+t]=q0.z; sX[ 3*Tv+t]=q0.w;
        sX[ 4*Tv+t]=q1.x; sX[ 5*Tv+t]=q1.y; sX[ 6*Tv+t]=q1.z; sX[ 7*Tv+t]=q1.w;
        sX[ 8*Tv+t]=q2.x; sX[ 9*Tv+t]=q2.y; sX[10*Tv+t]=q2.z; sX[11*Tv+t]=q2.w;
        sX[12*Tv+t]=q3.x; sX[13*Tv+t]=q3.y; sX[14*Tv+t]=q3.z; sX[15*Tv+t]=q3.w;
        sX[16*Tv+t]=q4.x; sX[17*Tv+t]=q4.y; sX[18*Tv+t]=q4.z; sX[19*Tv+t]=q4.w;
        sX[20*Tv+t]=q5.x; sX[21*Tv+t]=q5.y; sX[22*Tv+t]=q5.z; sX[23*Tv+t]=q5.w;
        sX[24*Tv+t]=q6.x; sX[25*Tv+t]=q6.y; sX[26*Tv+t]=q6.z; sX[27*Tv+t]=q6.w;
        sX[28*Tv+t]=q7.x; sX[29*Tv+t]=q7.y; sX[30*Tv+t]=q7.z; sX[31*Tv+t]=q7.w;
    }
    __syncthreads();

    // ---- GEMM1: O[32c][t], two 4-row tiles SHARING x-reads ----
    float oA[16], oB[16];
    #pragma unroll
    for (int i = 0; i < 16; ++i) { oA[i] = 0.f; oB[i] = 0.f; }
    const int cA = cl * 4;
    const int cB = 16 + cl * 4;
    #pragma unroll
    for (int k0 = 0; k0 < 32; k0 += 4) {
        const float4 x0 = *(const float4*)&sX[(k0+0)*Tv + t0];
        const float4 x1 = *(const float4*)&sX[(k0+1)*Tv + t0];
        const float4 x2 = *(const float4*)&sX[(k0+2)*Tv + t0];
        const float4 x3 = *(const float4*)&sX[(k0+3)*Tv + t0];
        { const float4 a = *(const float4*)&sM[(cA+0)*36 + k0]; GEMM_CC(oA,0,a) }
        { const float4 a = *(const float4*)&sM[(cA+1)*36 + k0]; GEMM_CC(oA,1,a) }
        { const float4 a = *(const float4*)&sM[(cA+2)*36 + k0]; GEMM_CC(oA,2,a) }
        { const float4 a = *(const float4*)&sM[(cA+3)*36 + k0]; GEMM_CC(oA,3,a) }
        { const float4 a = *(const float4*)&sM[(cB+0)*36 + k0]; GEMM_CC(oB,0,a) }
        { const float4 a = *(const float4*)&sM[(cB+1)*36 + k0]; GEMM_CC(oB,1,a) }
        { const float4 a = *(const float4*)&sM[(cB+2)*36 + k0]; GEMM_CC(oB,2,a) }
        { const float4 a = *(const float4*)&sM[(cB+3)*36 + k0]; GEMM_CC(oB,3,a) }
    }

    // ---- mask ----
    #pragma unroll
    for (int jt = 0; jt < 4; ++jt) {
        if (t0 + jt >= limit) {
            #pragma unroll
            for (int cc = 0; cc < 4; ++cc) { oA[cc*4+jt] = -INFINITY; oB[cc*4+jt] = -INFINITY; }
        }
    }

    // ---- stats pass 1: per-(wave,c) max ----
    #pragma unroll
    for (int cc = 0; cc < 4; ++cc) {
        float mA = fmaxf(fmaxf(oA[cc*4+0], oA[cc*4+1]), fmaxf(oA[cc*4+2], oA[cc*4+3]));
        float mB = fmaxf(fmaxf(oB[cc*4+0], oB[cc*4+1]), fmaxf(oB[cc*4+2], oB[cc*4+3]));
        #pragma unroll
        for (int s = 1; s < 16; s <<= 1) {
            mA = fmaxf(mA, __shfl_xor(mA, s));
            mB = fmaxf(mB, __shfl_xor(mB, s));
        }
        if (tl == 0) { sPart[w][cA + cc] = mA; sPart[w][cB + cc] = mB; }
    }
    __syncthreads();
    if (tid < DCv) {
        float m = sPart[0][tid];
        #pragma unroll
        for (int ww = 1; ww < 8; ++ww) m = fmaxf(m, sPart[ww][tid]);
        sMx[tid] = m;
    }
    __syncthreads();

    // ---- exp + pass 2: per-(wave,c) sum ----
    #pragma unroll
    for (int cc = 0; cc < 4; ++cc) {
        const float mxA = sMx[cA + cc], mxB = sMx[cB + cc];
        float sA = 0.f, sB = 0.f;
        #pragma unroll
        for (int jt = 0; jt < 4; ++jt) {
            oA[cc*4+jt] = __expf(oA[cc*4+jt] - mxA); sA += oA[cc*4+jt];
            oB[cc*4+jt] = __expf(oB[cc*4+jt] - mxB); sB += oB[cc*4+jt];
        }
        #pragma unroll
        for (int s = 1; s < 16; s <<= 1) {
            sA += __shfl_xor(sA, s);
            sB += __shfl_xor(sB, s);
        }
        if (tl == 0) { sPart[w][cA + cc] = sA; sPart[w][cB + cc] = sB; }
    }
    __syncthreads();
    if (tid < DCv) {
        float z = 0.f;
        #pragma unroll
        for (int ww = 0; ww < 8; ++ww) z += sPart[ww][tid];
        sRZ[tid] = 1.f / z;
    }
    __syncthreads();

    // ---- P = e * rz -> overwrite sX ----
    #pragma unroll
    for (int cc = 0; cc < 4; ++cc) {
        const float rA = sRZ[cA + cc], rB = sRZ[cB + cc];
        float4 pA, pB;
        pA.x = oA[cc*4+0]*rA; pA.y = oA[cc*4+1]*rA; pA.z = oA[cc*4+2]*rA; pA.w = oA[cc*4+3]*rA;
        pB.x = oB[cc*4+0]*rB; pB.y = oB[cc*4+1]*rB; pB.z = oB[cc*4+2]*rB; pB.w = oB[cc*4+3]*rB;
        *(float4*)&sX[(cA + cc)*Tv + t0] = pA;
        *(float4*)&sX[(cB + cc)*Tv + t0] = pB;
    }
    __syncthreads();

    // ---- GEMM2: OUT[64oc][t] in TWO 8-row-tile iterations (x-reads shared) ----
    #pragma unroll 1
    for (int it = 0; it < 2; ++it) {
        const int oc0 = it * 32 + cl * 8;

        float acc[32];
        #pragma unroll
        for (int i = 0; i < 32; ++i) acc[i] = 0.f;

        #pragma unroll
        for (int k0 = 0; k0 < 32; k0 += 4) {
            const float4 x0 = *(const float4*)&sX[(k0+0)*Tv + t0];
            const float4 x1 = *(const float4*)&sX[(k0+1)*Tv + t0];
            const float4 x2 = *(const float4*)&sX[(k0+2)*Tv + t0];
            const float4 x3 = *(const float4*)&sX[(k0+3)*Tv + t0];
            { const float4 a = *(const float4*)&sW[(oc0+0)*36 + k0]; GEMM_CC(acc,0,a) }
            { const float4 a = *(const float4*)&sW[(oc0+1)*36 + k0]; GEMM_CC(acc,1,a) }
            { const float4 a = *(const float4*)&sW[(oc0+2)*36 + k0]; GEMM_CC(acc,2,a) }
            { const float4 a = *(const float4*)&sW[(oc0+3)*36 + k0]; GEMM_CC(acc,3,a) }
            { const float4 a = *(const float4*)&sW[(oc0+4)*36 + k0]; GEMM_CC(acc,4,a) }
            { const float4 a = *(const float4*)&sW[(oc0+5)*36 + k0]; GEMM_CC(acc,5,a) }
            { const float4 a = *(const float4*)&sW[(oc0+6)*36 + k0]; GEMM_CC(acc,6,a) }
            { const float4 a = *(const float4*)&sW[(oc0+7)*36 + k0]; GEMM_CC(acc,7,a) }
        }

        const float* rp = inp + ((size_t)(b * Cv + oc0) * Fv + f) * Tv + t0;
        float*       po = out + ((size_t)(b * Cv + oc0) * Fv + f) * Tv + t0;
        #pragma unroll
        for (int r = 0; r < 8; ++r) {
            const float4 rv = *(const float4*)&rp[(size_t)r * FT];
            const float bb = sB2[oc0 + r];
            float z0 = acc[r*4+0] + bb, z1 = acc[r*4+1] + bb;
            float z2 = acc[r*4+2] + bb, z3 = acc[r*4+3] + bb;
            z0 = z0 >= 0.f ? z0 : alpha2 * z0;
            z1 = z1 >= 0.f ? z1 : alpha2 * z1;
            z2 = z2 >= 0.f ? z2 : alpha2 * z2;
            z3 = z3 >= 0.f ? z3 : alpha2 * z3;
            float4 o4; o4.x = z0 + rv.x; o4.y = z1 + rv.y;
            o4.z = z2 + rv.z; o4.w = z3 + rv.w;
            *(float4*)&po[(size_t)r * FT] = o4;
        }
    }
}

extern "C" void kernel_launch(void* const* d_in, const int* in_sizes, int n_in,
                              void* d_out, int out_size, void* d_ws, size_t ws_size,
                              hipStream_t stream) {
    const float* inp = (const float*)d_in[0];
    const float* w1  = (const float*)d_in[1];
    const float* b1  = (const float*)d_in[2];
    const float* g1  = (const float*)d_in[3];
    const float* be1 = (const float*)d_in[4];
    const float* m1  = (const float*)d_in[5];
    const float* v1  = (const float*)d_in[6];
    const float* a1  = (const float*)d_in[7];
    const float* wp  = (const float*)d_in[8];
    const float* bp  = (const float*)d_in[9];
    const float* g2  = (const float*)d_in[10];
    const float* be2 = (const float*)d_in[11];
    const float* m2  = (const float*)d_in[12];
    const float* v2  = (const float*)d_in[13];
    const float* a2  = (const float*)d_in[14];

    float* Qws   = (float*)d_ws;                            // 8,388,608 f = 33.6 MB
    float* Mfull = Qws + (size_t)Bv * Fv * Tv * DCv;        //   524,288 f =  2.1 MB

    kc1_conv<<<dim3(Bv * Fv * 2), dim3(256), 0, stream>>>(
        inp, w1, b1, g1, be1, m1, v1, a1, Qws);
    km_build<<<dim3(Bv * Fv), dim3(256), 0, stream>>>(Qws, Mfull);
    kf_fused<<<dim3(Bv * Fv), dim3(512), 0, stream>>>(
        inp, Qws, Mfull, wp, bp, g2, be2, m2, v2, a2, (float*)d_out);
}

// Round 20
// 87.266 us; speedup vs baseline: 1.1015x; 1.0008x over previous
//
#include <hip/hip_runtime.h>
#include <math.h>

#define Bv  4
#define Cv  64
#define DCv 32
#define Fv  128
#define Tv  512
#define FT  (Fv * 512)

// ---------------------------------------------------------------------------
// KC1: conv1, 8-row x 4-t register tile (r17-measured ~27-30 us). grid
// (bf, t-half) = 1024 x 256 (4 waves). Per k: 1 global b128 (32 FMA) +
// 2 broadcast LDS b128. BN fold computed INLINE.  [BYTE-IDENTICAL to r19]
// ---------------------------------------------------------------------------
__global__ __launch_bounds__(256, 4)
void kc1_conv(const float* __restrict__ inp,
              const float* __restrict__ w1, const float* __restrict__ b1,
              const float* __restrict__ g1, const float* __restrict__ be1,
              const float* __restrict__ m1, const float* __restrict__ v1,
              const float* __restrict__ a1,
              float* __restrict__ Qws)
{
    __shared__ __align__(16) float sW[Cv * DCv];   // 8 KB [k][c]
    __shared__ float sB[DCv];

    const int tid = threadIdx.x;
    const int bid = blockIdx.x;
    const int h   = bid & 1;
    const int bf  = bid >> 1;
    const int b   = bf >> 7;
    const int f   = bf & 127;

    #pragma unroll
    for (int i = 0; i < 8; ++i) {
        const int e = tid * 8 + i;
        const int c = e & 31, k = e >> 5;
        sW[e] = w1[c * Cv + k] * (g1[c] * rsqrtf(v1[c] + 1e-5f));
    }
    if (tid < DCv) {
        const float s = g1[tid] * rsqrtf(v1[tid] + 1e-5f);
        sB[tid] = (b1[tid] - m1[tid]) * s + be1[tid];
    }
    const float alpha1 = a1[0];
    __syncthreads();

    const int w  = tid >> 6, l = tid & 63;
    const int tl = l & 15, cl = l >> 4;
    const int r0 = cl * 8;
    const int t0 = h * 256 + w * 64 + tl * 4;

    const float* px = inp + (size_t)(b * Cv) * FT + f * 512 + t0;

    float acc[32];
    #pragma unroll
    for (int i = 0; i < 32; ++i) acc[i] = 0.f;

    #pragma unroll 8
    for (int k = 0; k < Cv; ++k) {
        const float4 x   = *(const float4*)&px[(size_t)k * FT];
        const float4 a0  = *(const float4*)&sW[k * DCv + r0];
        const float4 a1v = *(const float4*)&sW[k * DCv + r0 + 4];
        acc[0*4+0] = fmaf(a0.x, x.x, acc[0*4+0]); acc[0*4+1] = fmaf(a0.x, x.y, acc[0*4+1]);
        acc[0*4+2] = fmaf(a0.x, x.z, acc[0*4+2]); acc[0*4+3] = fmaf(a0.x, x.w, acc[0*4+3]);
        acc[1*4+0] = fmaf(a0.y, x.x, acc[1*4+0]); acc[1*4+1] = fmaf(a0.y, x.y, acc[1*4+1]);
        acc[1*4+2] = fmaf(a0.y, x.z, acc[1*4+2]); acc[1*4+3] = fmaf(a0.y, x.w, acc[1*4+3]);
        acc[2*4+0] = fmaf(a0.z, x.x, acc[2*4+0]); acc[2*4+1] = fmaf(a0.z, x.y, acc[2*4+1]);
        acc[2*4+2] = fmaf(a0.z, x.z, acc[2*4+2]); acc[2*4+3] = fmaf(a0.z, x.w, acc[2*4+3]);
        acc[3*4+0] = fmaf(a0.w, x.x, acc[3*4+0]); acc[3*4+1] = fmaf(a0.w, x.y, acc[3*4+1]);
        acc[3*4+2] = fmaf(a0.w, x.z, acc[3*4+2]); acc[3*4+3] = fmaf(a0.w, x.w, acc[3*4+3]);
        acc[4*4+0] = fmaf(a1v.x, x.x, acc[4*4+0]); acc[4*4+1] = fmaf(a1v.x, x.y, acc[4*4+1]);
        acc[4*4+2] = fmaf(a1v.x, x.z, acc[4*4+2]); acc[4*4+3] = fmaf(a1v.x, x.w, acc[4*4+3]);
        acc[5*4+0] = fmaf(a1v.y, x.x, acc[5*4+0]); acc[5*4+1] = fmaf(a1v.y, x.y, acc[5*4+1]);
        acc[5*4+2] = fmaf(a1v.y, x.z, acc[5*4+2]); acc[5*4+3] = fmaf(a1v.y, x.w, acc[5*4+3]);
        acc[6*4+0] = fmaf(a1v.z, x.x, acc[6*4+0]); acc[6*4+1] = fmaf(a1v.z, x.y, acc[6*4+1]);
        acc[6*4+2] = fmaf(a1v.z, x.z, acc[6*4+2]); acc[6*4+3] = fmaf(a1v.z, x.w, acc[6*4+3]);
        acc[7*4+0] = fmaf(a1v.w, x.x, acc[7*4+0]); acc[7*4+1] = fmaf(a1v.w, x.y, acc[7*4+1]);
        acc[7*4+2] = fmaf(a1v.w, x.z, acc[7*4+2]); acc[7*4+3] = fmaf(a1v.w, x.w, acc[7*4+3]);
    }

    const float b0 = sB[r0+0], b1_ = sB[r0+1], b2 = sB[r0+2], b3 = sB[r0+3];
    const float b4 = sB[r0+4], b5  = sB[r0+5], b6 = sB[r0+6], b7 = sB[r0+7];
    #pragma unroll
    for (int j = 0; j < 4; ++j) {
        float z0 = acc[0*4+j] + b0, z1 = acc[1*4+j] + b1_;
        float z2 = acc[2*4+j] + b2, z3 = acc[3*4+j] + b3;
        float z4 = acc[4*4+j] + b4, z5 = acc[5*4+j] + b5;
        float z6 = acc[6*4+j] + b6, z7 = acc[7*4+j] + b7;
        z0 = z0 >= 0.f ? z0 : alpha1 * z0;  z1 = z1 >= 0.f ? z1 : alpha1 * z1;
        z2 = z2 >= 0.f ? z2 : alpha1 * z2;  z3 = z3 >= 0.f ? z3 : alpha1 * z3;
        z4 = z4 >= 0.f ? z4 : alpha1 * z4;  z5 = z5 >= 0.f ? z5 : alpha1 * z5;
        z6 = z6 >= 0.f ? z6 : alpha1 * z6;  z7 = z7 >= 0.f ? z7 : alpha1 * z7;
        float4 v0; v0.x = z0; v0.y = z1; v0.z = z2; v0.w = z3;
        float4 v1; v1.x = z4; v1.y = z5; v1.z = z6; v1.w = z7;
        float* qg = Qws + ((size_t)bf * Tv + t0 + j) * DCv + r0;
        *(float4*)&qg[0] = v0;
        *(float4*)&qg[4] = v1;
    }
}

// ---------------------------------------------------------------------------
// KM: M = Q Q^T / sqrt(32). One block per bf. Proven (~9 us). [IDENTICAL]
// ---------------------------------------------------------------------------
__global__ __launch_bounds__(256)
void km_build(const float* __restrict__ Qws, float* __restrict__ Mfull)
{
    __shared__ __align__(16) float sP[4][1024];  // 16 KB

    const int tid   = threadIdx.x;
    const int bf    = blockIdx.x;
    const int slice = tid >> 6;
    const int l     = tid & 63;
    const int c1b   = l >> 3;
    const int c2b   = l & 7;

    const float* qp = Qws + ((size_t)bf * Tv + slice * 128) * DCv;
    float4 r0 = {0,0,0,0}, r1 = {0,0,0,0}, r2 = {0,0,0,0}, r3 = {0,0,0,0};
    #pragma unroll 4
    for (int i = 0; i < 128; ++i) {
        const float4 qa = *(const float4*)&qp[i * 32 + c1b * 4];
        const float4 qb = *(const float4*)&qp[i * 32 + c2b * 4];
        r0.x = fmaf(qa.x, qb.x, r0.x); r0.y = fmaf(qa.x, qb.y, r0.y);
        r0.z = fmaf(qa.x, qb.z, r0.z); r0.w = fmaf(qa.x, qb.w, r0.w);
        r1.x = fmaf(qa.y, qb.x, r1.x); r1.y = fmaf(qa.y, qb.y, r1.y);
        r1.z = fmaf(qa.y, qb.z, r1.z); r1.w = fmaf(qa.y, qb.w, r1.w);
        r2.x = fmaf(qa.z, qb.x, r2.x); r2.y = fmaf(qa.z, qb.y, r2.y);
        r2.z = fmaf(qa.z, qb.z, r2.z); r2.w = fmaf(qa.z, qb.w, r2.w);
        r3.x = fmaf(qa.w, qb.x, r3.x); r3.y = fmaf(qa.w, qb.y, r3.y);
        r3.z = fmaf(qa.w, qb.z, r3.z); r3.w = fmaf(qa.w, qb.w, r3.w);
    }
    *(float4*)&sP[slice][(c1b * 4 + 0) * DCv + c2b * 4] = r0;
    *(float4*)&sP[slice][(c1b * 4 + 1) * DCv + c2b * 4] = r1;
    *(float4*)&sP[slice][(c1b * 4 + 2) * DCv + c2b * 4] = r2;
    *(float4*)&sP[slice][(c1b * 4 + 3) * DCv + c2b * 4] = r3;
    __syncthreads();

    const float INV = 0.17677669529663687f;  // 1/sqrt(32)
    float4 v0 = *(const float4*)&sP[0][tid * 4];
    float4 v1 = *(const float4*)&sP[1][tid * 4];
    float4 v2 = *(const float4*)&sP[2][tid * 4];
    float4 v3 = *(const float4*)&sP[3][tid * 4];
    float4 o;
    o.x = ((v0.x + v1.x) + (v2.x + v3.x)) * INV;
    o.y = ((v0.y + v1.y) + (v2.y + v3.y)) * INV;
    o.z = ((v0.z + v1.z) + (v2.z + v3.z)) * INV;
    o.w = ((v0.w + v1.w) + (v2.w + v3.w)) * INV;
    *(float4*)&Mfull[(size_t)bf * 1024 + tid * 4] = o;
}

// ---------------------------------------------------------------------------
// KF: fused O=M*Q -> mask -> ONLINE softmax (1 pass, 2 barriers, was 4) ->
// P -> OUT=W2*P+B2 -> PReLU -> +residual. Wave computes (m_w, s_w) in one
// pass; combine computes m, Z = sum s_w exp(m_w - m); per-wave P-scale =
// exp(m_w - m)/Z folds into the existing multiply. -inf wave-rows clamped
// to -1e30 so all exp terms collapse to 0 (wave 7 fully masked when f<64).
// ---------------------------------------------------------------------------
#define GEMM_CC(ACC, cc, a)                                       \
    ACC[(cc)*4+0] = fmaf(a.x, x0.x, ACC[(cc)*4+0]);               \
    ACC[(cc)*4+0] = fmaf(a.y, x1.x, ACC[(cc)*4+0]);               \
    ACC[(cc)*4+0] = fmaf(a.z, x2.x, ACC[(cc)*4+0]);               \
    ACC[(cc)*4+0] = fmaf(a.w, x3.x, ACC[(cc)*4+0]);               \
    ACC[(cc)*4+1] = fmaf(a.x, x0.y, ACC[(cc)*4+1]);               \
    ACC[(cc)*4+1] = fmaf(a.y, x1.y, ACC[(cc)*4+1]);               \
    ACC[(cc)*4+1] = fmaf(a.z, x2.y, ACC[(cc)*4+1]);               \
    ACC[(cc)*4+1] = fmaf(a.w, x3.y, ACC[(cc)*4+1]);               \
    ACC[(cc)*4+2] = fmaf(a.x, x0.z, ACC[(cc)*4+2]);               \
    ACC[(cc)*4+2] = fmaf(a.y, x1.z, ACC[(cc)*4+2]);               \
    ACC[(cc)*4+2] = fmaf(a.z, x2.z, ACC[(cc)*4+2]);               \
    ACC[(cc)*4+2] = fmaf(a.w, x3.z, ACC[(cc)*4+2]);               \
    ACC[(cc)*4+3] = fmaf(a.x, x0.w, ACC[(cc)*4+3]);               \
    ACC[(cc)*4+3] = fmaf(a.y, x1.w, ACC[(cc)*4+3]);               \
    ACC[(cc)*4+3] = fmaf(a.z, x2.w, ACC[(cc)*4+3]);               \
    ACC[(cc)*4+3] = fmaf(a.w, x3.w, ACC[(cc)*4+3]);

__global__ __launch_bounds__(512, 2)
void kf_fused(const float* __restrict__ inp,
              const float* __restrict__ Qws, const float* __restrict__ Mfull,
              const float* __restrict__ wp, const float* __restrict__ bp,
              const float* __restrict__ g2, const float* __restrict__ be2,
              const float* __restrict__ m2, const float* __restrict__ v2,
              const float* __restrict__ a2,
              float* __restrict__ out)
{
    __shared__ __align__(16) float sX[DCv * Tv];   // 64 KB [k][t]: Q, then P
    __shared__ __align__(16) float sM[DCv * 36];   // 4.5 KB
    __shared__ __align__(16) float sW[Cv * 36];    // 9 KB
    __shared__ float sPartM[8][DCv], sPartS[8][DCv];
    __shared__ float sMx[DCv], sRZ[DCv];
    __shared__ float sB2[Cv];

    const int tid = threadIdx.x;
    const int bf  = blockIdx.x;
    const int b   = bf >> 7;
    const int f   = bf & 127;
    const int w   = tid >> 6;
    const int l   = tid & 63;
    const int tl  = l & 15;
    const int cl  = l >> 4;
    const int t0  = w * 64 + tl * 4;          // this lane's 4 t-columns
    const int limit = f + (Tv - Fv + 1);      // valid iff t < limit (385..512)
    const float alpha2 = a2[0];

    // ---- stage: q column, M, W2 (BN-folded inline), B2 ----
    const float* qg = Qws + ((size_t)bf * Tv + tid) * DCv;
    float4 q0 = *(const float4*)&qg[0],  q1 = *(const float4*)&qg[4];
    float4 q2 = *(const float4*)&qg[8],  q3 = *(const float4*)&qg[12];
    float4 q4 = *(const float4*)&qg[16], q5 = *(const float4*)&qg[20];
    float4 q6 = *(const float4*)&qg[24], q7 = *(const float4*)&qg[28];

    if (tid < 256) {
        const int c = tid >> 3, k0 = (tid & 7) << 2;
        float4 v = *(const float4*)&Mfull[(size_t)bf * 1024 + tid * 4];
        *(float4*)&sM[c * 36 + k0] = v;
    }
    {
        const int c = tid >> 3, k0 = (tid & 7) << 2;
        const float s = g2[c] * rsqrtf(v2[c] + 1e-5f);
        float4 v = *(const float4*)&wp[tid * 4];
        v.x *= s; v.y *= s; v.z *= s; v.w *= s;
        *(float4*)&sW[c * 36 + k0] = v;
    }
    if (tid < Cv) {
        const float s = g2[tid] * rsqrtf(v2[tid] + 1e-5f);
        sB2[tid] = (bp[tid] - m2[tid]) * s + be2[tid];
    }

    {
        const int t = tid;
        sX[ 0*Tv+t]=q0.x; sX[ 1*Tv+t]=q0.y; sX[ 2*Tv+t]=q0.z; sX[ 3*Tv+t]=q0.w;
        sX[ 4*Tv+t]=q1.x; sX[ 5*Tv+t]=q1.y; sX[ 6*Tv+t]=q1.z; sX[ 7*Tv+t]=q1.w;
        sX[ 8*Tv+t]=q2.x; sX[ 9*Tv+t]=q2.y; sX[10*Tv+t]=q2.z; sX[11*Tv+t]=q2.w;
        sX[12*Tv+t]=q3.x; sX[13*Tv+t]=q3.y; sX[14*Tv+t]=q3.z; sX[15*Tv+t]=q3.w;
        sX[16*Tv+t]=q4.x; sX[17*Tv+t]=q4.y; sX[18*Tv+t]=q4.z; sX[19*Tv+t]=q4.w;
        sX[20*Tv+t]=q5.x; sX[21*Tv+t]=q5.y; sX[22*Tv+t]=q5.z; sX[23*Tv+t]=q5.w;
        sX[24*Tv+t]=q6.x; sX[25*Tv+t]=q6.y; sX[26*Tv+t]=q6.z; sX[27*Tv+t]=q6.w;
        sX[28*Tv+t]=q7.x; sX[29*Tv+t]=q7.y; sX[30*Tv+t]=q7.z; sX[31*Tv+t]=q7.w;
    }
    __syncthreads();

    // ---- GEMM1: O[32c][t], two 4-row tiles SHARING x-reads ----
    float oA[16], oB[16];
    #pragma unroll
    for (int i = 0; i < 16; ++i) { oA[i] = 0.f; oB[i] = 0.f; }
    const int cA = cl * 4;
    const int cB = 16 + cl * 4;
    #pragma unroll
    for (int k0 = 0; k0 < 32; k0 += 4) {
        const float4 x0 = *(const float4*)&sX[(k0+0)*Tv + t0];
        const float4 x1 = *(const float4*)&sX[(k0+1)*Tv + t0];
        const float4 x2 = *(const float4*)&sX[(k0+2)*Tv + t0];
        const float4 x3 = *(const float4*)&sX[(k0+3)*Tv + t0];
        { const float4 a = *(const float4*)&sM[(cA+0)*36 + k0]; GEMM_CC(oA,0,a) }
        { const float4 a = *(const float4*)&sM[(cA+1)*36 + k0]; GEMM_CC(oA,1,a) }
        { const float4 a = *(const float4*)&sM[(cA+2)*36 + k0]; GEMM_CC(oA,2,a) }
        { const float4 a = *(const float4*)&sM[(cA+3)*36 + k0]; GEMM_CC(oA,3,a) }
        { const float4 a = *(const float4*)&sM[(cB+0)*36 + k0]; GEMM_CC(oB,0,a) }
        { const float4 a = *(const float4*)&sM[(cB+1)*36 + k0]; GEMM_CC(oB,1,a) }
        { const float4 a = *(const float4*)&sM[(cB+2)*36 + k0]; GEMM_CC(oB,2,a) }
        { const float4 a = *(const float4*)&sM[(cB+3)*36 + k0]; GEMM_CC(oB,3,a) }
    }

    // ---- mask ----
    #pragma unroll
    for (int jt = 0; jt < 4; ++jt) {
        if (t0 + jt >= limit) {
            #pragma unroll
            for (int cc = 0; cc < 4; ++cc) { oA[cc*4+jt] = -INFINITY; oB[cc*4+jt] = -INFINITY; }
        }
    }

    // ---- ONLINE wave stats (one pass): m_w, s_w = sum exp(O - m_w) ----
    float mwA[4], mwB[4];
    #pragma unroll
    for (int cc = 0; cc < 4; ++cc) {
        float mA = fmaxf(fmaxf(oA[cc*4+0], oA[cc*4+1]), fmaxf(oA[cc*4+2], oA[cc*4+3]));
        float mB = fmaxf(fmaxf(oB[cc*4+0], oB[cc*4+1]), fmaxf(oB[cc*4+2], oB[cc*4+3]));
        #pragma unroll
        for (int s = 1; s < 16; s <<= 1) {
            mA = fmaxf(mA, __shfl_xor(mA, s));
            mB = fmaxf(mB, __shfl_xor(mB, s));
        }
        mA = fmaxf(mA, -1e30f);   // clamp: fully-masked wave-row -> finite
        mB = fmaxf(mB, -1e30f);
        float sA = 0.f, sB = 0.f;
        #pragma unroll
        for (int jt = 0; jt < 4; ++jt) {
            oA[cc*4+jt] = __expf(oA[cc*4+jt] - mA); sA += oA[cc*4+jt];
            oB[cc*4+jt] = __expf(oB[cc*4+jt] - mB); sB += oB[cc*4+jt];
        }
        #pragma unroll
        for (int s = 1; s < 16; s <<= 1) {
            sA += __shfl_xor(sA, s);
            sB += __shfl_xor(sB, s);
        }
        mwA[cc] = mA; mwB[cc] = mB;
        if (tl == 0) {
            sPartM[w][cA + cc] = mA; sPartS[w][cA + cc] = sA;
            sPartM[w][cB + cc] = mB; sPartS[w][cB + cc] = sB;
        }
    }
    __syncthreads();
    if (tid < DCv) {
        float m = sPartM[0][tid];
        #pragma unroll
        for (int ww = 1; ww < 8; ++ww) m = fmaxf(m, sPartM[ww][tid]);
        float Z = 0.f;
        #pragma unroll
        for (int ww = 0; ww < 8; ++ww) Z += sPartS[ww][tid] * __expf(sPartM[ww][tid] - m);
        sMx[tid] = m;
        sRZ[tid] = 1.f / Z;
    }
    __syncthreads();

    // ---- P = e_w * exp(m_w - m) / Z -> overwrite sX ----
    #pragma unroll
    for (int cc = 0; cc < 4; ++cc) {
        const float scA = __expf(mwA[cc] - sMx[cA + cc]) * sRZ[cA + cc];
        const float scB = __expf(mwB[cc] - sMx[cB + cc]) * sRZ[cB + cc];
        float4 pA, pB;
        pA.x = oA[cc*4+0]*scA; pA.y = oA[cc*4+1]*scA; pA.z = oA[cc*4+2]*scA; pA.w = oA[cc*4+3]*scA;
        pB.x = oB[cc*4+0]*scB; pB.y = oB[cc*4+1]*scB; pB.z = oB[cc*4+2]*scB; pB.w = oB[cc*4+3]*scB;
        *(float4*)&sX[(cA + cc)*Tv + t0] = pA;
        *(float4*)&sX[(cB + cc)*Tv + t0] = pB;
    }
    __syncthreads();

    // ---- GEMM2: OUT[64oc][t] in TWO 8-row-tile iterations (x-reads shared) ----
    #pragma unroll 1
    for (int it = 0; it < 2; ++it) {
        const int oc0 = it * 32 + cl * 8;

        float acc[32];
        #pragma unroll
        for (int i = 0; i < 32; ++i) acc[i] = 0.f;

        #pragma unroll
        for (int k0 = 0; k0 < 32; k0 += 4) {
            const float4 x0 = *(const float4*)&sX[(k0+0)*Tv + t0];
            const float4 x1 = *(const float4*)&sX[(k0+1)*Tv + t0];
            const float4 x2 = *(const float4*)&sX[(k0+2)*Tv + t0];
            const float4 x3 = *(const float4*)&sX[(k0+3)*Tv + t0];
            { const float4 a = *(const float4*)&sW[(oc0+0)*36 + k0]; GEMM_CC(acc,0,a) }
            { const float4 a = *(const float4*)&sW[(oc0+1)*36 + k0]; GEMM_CC(acc,1,a) }
            { const float4 a = *(const float4*)&sW[(oc0+2)*36 + k0]; GEMM_CC(acc,2,a) }
            { const float4 a = *(const float4*)&sW[(oc0+3)*36 + k0]; GEMM_CC(acc,3,a) }
            { const float4 a = *(const float4*)&sW[(oc0+4)*36 + k0]; GEMM_CC(acc,4,a) }
            { const float4 a = *(const float4*)&sW[(oc0+5)*36 + k0]; GEMM_CC(acc,5,a) }
            { const float4 a = *(const float4*)&sW[(oc0+6)*36 + k0]; GEMM_CC(acc,6,a) }
            { const float4 a = *(const float4*)&sW[(oc0+7)*36 + k0]; GEMM_CC(acc,7,a) }
        }

        const float* rp = inp + ((size_t)(b * Cv + oc0) * Fv + f) * Tv + t0;
        float*       po = out + ((size_t)(b * Cv + oc0) * Fv + f) * Tv + t0;
        #pragma unroll
        for (int r = 0; r < 8; ++r) {
            const float4 rv = *(const float4*)&rp[(size_t)r * FT];
            const float bb = sB2[oc0 + r];
            float z0 = acc[r*4+0] + bb, z1 = acc[r*4+1] + bb;
            float z2 = acc[r*4+2] + bb, z3 = acc[r*4+3] + bb;
            z0 = z0 >= 0.f ? z0 : alpha2 * z0;
            z1 = z1 >= 0.f ? z1 : alpha2 * z1;
            z2 = z2 >= 0.f ? z2 : alpha2 * z2;
            z3 = z3 >= 0.f ? z3 : alpha2 * z3;
            float4 o4; o4.x = z0 + rv.x; o4.y = z1 + rv.y;
            o4.z = z2 + rv.z; o4.w = z3 + rv.w;
            *(float4*)&po[(size_t)r * FT] = o4;
        }
    }
}

extern "C" void kernel_launch(void* const* d_in, const int* in_sizes, int n_in,
                              void* d_out, int out_size, void* d_ws, size_t ws_size,
                              hipStream_t stream) {
    const float* inp = (const float*)d_in[0];
    const float* w1  = (const float*)d_in[1];
    const float* b1  = (const float*)d_in[2];
    const float* g1  = (const float*)d_in[3];
    const float* be1 = (const float*)d_in[4];
    const float* m1  = (const float*)d_in[5];
    const float* v1  = (const float*)d_in[6];
    const float* a1  = (const float*)d_in[7];
    const float* wp  = (const float*)d_in[8];
    const float* bp  = (const float*)d_in[9];
    const float* g2  = (const float*)d_in[10];
    const float* be2 = (const float*)d_in[11];
    const float* m2  = (const float*)d_in[12];
    const float* v2  = (const float*)d_in[13];
    const float* a2  = (const float*)d_in[14];

    float* Qws   = (float*)d_ws;                            // 8,388,608 f = 33.6 MB
    float* Mfull = Qws + (size_t)Bv * Fv * Tv * DCv;        //   524,288 f =  2.1 MB

    kc1_conv<<<dim3(Bv * Fv * 2), dim3(256), 0, stream>>>(
        inp, w1, b1, g1, be1, m1, v1, a1, Qws);
    km_build<<<dim3(Bv * Fv), dim3(256), 0, stream>>>(Qws, Mfull);
    kf_fused<<<dim3(Bv * Fv), dim3(512), 0, stream>>>(
        inp, Qws, Mfull, wp, bp, g2, be2, m2, v2, a2, (float*)d_out);
}